// Round 7
// baseline (248.538 us; speedup 1.0000x reference)
//
#include <hip/hip_runtime.h>
#include <hip/hip_bf16.h>
#include <math.h>

#define BDIM 512
#define DDIM 512
#define CDIM 100000
#define NC 64
#define NCHUNK ((CDIM + NC - 1) / NC)   // 1563
#define CPAD (NCHUNK * NC)              // 100032 padded classes
#define CTILE 128                       // classes per k_wt block

typedef __attribute__((ext_vector_type(8))) short short8;
typedef __attribute__((ext_vector_type(4))) float f32x4;

__device__ __forceinline__ unsigned short f2bf(float f) {
  unsigned int u = __builtin_bit_cast(unsigned int, f);
  u = (u + 0x7FFFu + ((u >> 16) & 1u)) >> 16;   // RNE
  return (unsigned short)u;
}

__device__ __forceinline__ void gl_lds16(const unsigned short* g, unsigned short* l) {
  __builtin_amdgcn_global_load_lds(
      (const __attribute__((address_space(1))) void*)g,
      (__attribute__((address_space(3))) void*)l, 16, 0, 0);
}

// ---- kernel 1: L2-normalize feature rows, emit bf16 [B][D] ----
__global__ void k_rownorm(const float* __restrict__ x, unsigned short* __restrict__ a) {
  const int b = blockIdx.x;
  const int tid = threadIdx.x;
  const float* row = x + (size_t)b * DDIM;
  float v0 = row[tid], v1 = row[tid + 256];
  float ss = v0 * v0 + v1 * v1;
  #pragma unroll
  for (int m = 1; m < 64; m <<= 1) ss += __shfl_xor(ss, m);
  __shared__ float sred[4];
  __shared__ float sinv;
  if ((tid & 63) == 0) sred[tid >> 6] = ss;
  __syncthreads();
  if (tid == 0) {
    float s = sred[0] + sred[1] + sred[2] + sred[3];
    sinv = 1.f / fmaxf(sqrtf(s), 1e-12f);
  }
  __syncthreads();
  const float inv = sinv;
  a[(size_t)b * DDIM + tid] = f2bf(v0 * inv);
  a[(size_t)b * DDIM + tid + 256] = f2bf(v1 * inv);
}

// ---- kernel 1b: transpose+convert w [D][C] fp32 -> w_t [CPAD][D] bf16, + invwn ----
// Pure streaming: 512B-contiguous reads, LDS tile transpose, 128B-coalesced
// class-row writes. Register-light -> deep MLP -> HBM BW-bound.
__global__ __launch_bounds__(512)
void k_wt(const float* __restrict__ w, unsigned short* __restrict__ wt,
          float* __restrict__ invwn) {
  __shared__ float tile[64][CTILE + 4];
  const int t = threadIdx.x;
  const int c0w = blockIdx.x * CTILE;
  const int rd_d = t >> 3;            // 0..63
  const int rd_c = (t & 7) * 16;      // col segment base
  const int wc = t >> 2;              // 0..127 class
  const int wh = t & 3;               // 0..3 d-quarter
  float ss = 0.f;

  for (int ch = 0; ch < 8; ch++) {
    const int d0 = ch * 64;
    float4 r[4];
    #pragma unroll
    for (int j = 0; j < 4; j++) {
      const int c = c0w + rd_c + j * 4;
      if (c < CDIM)
        r[j] = *reinterpret_cast<const float4*>(w + (size_t)(d0 + rd_d) * CDIM + c);
      else
        r[j] = (float4){0.f, 0.f, 0.f, 0.f};
    }
    #pragma unroll
    for (int j = 0; j < 4; j++)
      *reinterpret_cast<float4*>(&tile[rd_d][rd_c + j * 4]) = r[j];
    __syncthreads();

    short8 o0, o1;
    #pragma unroll
    for (int j = 0; j < 8; j++) {
      const float v = tile[wh * 16 + j][wc];
      ss += v * v;
      o0[j] = (short)f2bf(v);
    }
    #pragma unroll
    for (int j = 0; j < 8; j++) {
      const float v = tile[wh * 16 + 8 + j][wc];
      ss += v * v;
      o1[j] = (short)f2bf(v);
    }
    if (c0w + wc < CDIM) {
      unsigned short* dst = wt + ((size_t)(c0w + wc) << 9) + d0 + wh * 16;
      *reinterpret_cast<short8*>(dst) = o0;
      *reinterpret_cast<short8*>(dst + 8) = o1;
    }
    __syncthreads();
  }
  ss += __shfl_xor(ss, 1);
  ss += __shfl_xor(ss, 2);
  if (wh == 0 && c0w + wc < CDIM)
    invwn[c0w + wc] = 1.f / fmaxf(sqrtf(ss), 1e-12f);
}

// ---- kernel 2: GEMM + margin + per-chunk LSE partials ----
// B-tile: 64 class rows of w_t (1KB contiguous each) DMA'd via global_load_lds,
// pre-swizzled source + linear dest + XOR-swizzled reads (2-way = free).
// One barrier, then barrier-free unrolled K-loop (af from L2-resident a).
__global__ __launch_bounds__(512, 4)
void k_main(const unsigned short* __restrict__ a,
            const unsigned short* __restrict__ wt,
            const float* __restrict__ invwn,
            const long long* __restrict__ label,
            float2* __restrict__ part,
            float* __restrict__ labellogit) {
  __shared__ __align__(16) unsigned short blds[NC][DDIM];   // 64 KB
  __shared__ float invwn_sh[NC];

  const int t = threadIdx.x;
  const int chunk = blockIdx.x;
  const int c0 = chunk * NC;

  const int wave = t >> 6;
  const int lane = t & 63;
  const int lhi = lane >> 4;   // 0..3
  const int llo = lane & 15;   // 0..15

  if (t < NC) invwn_sh[t] = invwn[c0 + t];     // padded array, in-bounds

  // stage 8 class rows per wave; source pre-swizzled so linear LDS dest gets
  // swizzled layout: LDS elem le of row c holds global elem le ^ ((c&7)<<3)
  #pragma unroll
  for (int i = 0; i < 8; i++) {
    const int c = wave * 8 + i;                // c & 7 == i
    gl_lds16(wt + ((size_t)(c0 + c) << 9) + ((lane ^ i) << 3), &blds[c][0]);
  }
  asm volatile("s_waitcnt vmcnt(0)" ::: "memory");
  __syncthreads();

  f32x4 acc[4][4];
  #pragma unroll
  for (int i = 0; i < 4; i++)
    #pragma unroll
    for (int j = 0; j < 4; j++)
      acc[i][j] = (f32x4){0.f, 0.f, 0.f, 0.f};

  const unsigned short* ab0 = a + (size_t)(wave * 64 + 0 * 16 + llo) * DDIM + (lhi << 3);
  const unsigned short* ab1 = a + (size_t)(wave * 64 + 1 * 16 + llo) * DDIM + (lhi << 3);
  const unsigned short* ab2 = a + (size_t)(wave * 64 + 2 * 16 + llo) * DDIM + (lhi << 3);
  const unsigned short* ab3 = a + (size_t)(wave * 64 + 3 * 16 + llo) * DDIM + (lhi << 3);

  #pragma unroll
  for (int step = 0; step < 16; step++) {
    const int koff = step * 32;                 // compile-time imm offsets
    short8 af[4], bfr[4];
    af[0] = *reinterpret_cast<const short8*>(ab0 + koff);
    af[1] = *reinterpret_cast<const short8*>(ab1 + koff);
    af[2] = *reinterpret_cast<const short8*>(ab2 + koff);
    af[3] = *reinterpret_cast<const short8*>(ab3 + koff);
    #pragma unroll
    for (int cf = 0; cf < 4; cf++) {
      const int c = cf * 16 + llo;
      bfr[cf] = *reinterpret_cast<const short8*>(
          &blds[c][(koff + (lhi << 3)) ^ ((c & 7) << 3)]);
    }
    #pragma unroll
    for (int rf = 0; rf < 4; rf++)
      #pragma unroll
      for (int cf = 0; cf < 4; cf++)
        acc[rf][cf] = __builtin_amdgcn_mfma_f32_16x16x32_bf16(af[rf], bfr[cf], acc[rf][cf], 0, 0, 0);
  }

  // ---- epilogue: logits -> per-row (max, sumexp) over this chunk's 64 classes ----
  #pragma unroll
  for (int rf = 0; rf < 4; rf++) {
    #pragma unroll
    for (int r = 0; r < 4; r++) {
      const int row = wave * 64 + rf * 16 + (lhi << 2) + r;
      const int lab = (int)label[row];
      float vals[4];
      float mloc = -INFINITY;
      #pragma unroll
      for (int cf = 0; cf < 4; cf++) {
        const int cg = c0 + cf * 16 + llo;
        float cs = acc[rf][cf][r] * invwn_sh[cf * 16 + llo];
        cs = fminf(fmaxf(cs, -1.f), 1.f);
        float lg = 64.f * cs;
        if (cg == lab) { lg = 64.f * (cs - 0.35f); labellogit[row] = lg; }
        if (cg >= CDIM) lg = -INFINITY;
        vals[cf] = lg;
        mloc = fmaxf(mloc, lg);
      }
      float m = mloc;
      #pragma unroll
      for (int msk = 1; msk < 16; msk <<= 1) m = fmaxf(m, __shfl_xor(m, msk));
      float s = 0.f;
      #pragma unroll
      for (int cf = 0; cf < 4; cf++) s += __expf(vals[cf] - m);
      #pragma unroll
      for (int msk = 1; msk < 16; msk <<= 1) s += __shfl_xor(s, msk);
      if (llo == 0) part[(size_t)chunk * BDIM + row] = make_float2(m, s);
    }
  }
}

// ---- kernel 3: per-row online-LSE combine over chunks (part is [chunk][row]) ----
__global__ void k_rowreduce(const float2* __restrict__ part,
                            const float* __restrict__ labellogit,
                            float* __restrict__ rowloss) {
  const int row = blockIdx.x;
  const int tid = threadIdx.x;
  float m = -INFINITY, s = 0.f;
  for (int ch = tid; ch < NCHUNK; ch += 256) {
    float2 p = part[(size_t)ch * BDIM + row];
    float nm = fmaxf(m, p.x);
    s = s * __expf(m - nm) + p.y * __expf(p.x - nm);
    m = nm;
  }
  #pragma unroll
  for (int msk = 1; msk < 64; msk <<= 1) {
    float om = __shfl_xor(m, msk), os = __shfl_xor(s, msk);
    float nm = fmaxf(m, om);
    s = s * __expf(m - nm) + os * __expf(om - nm);
    m = nm;
  }
  __shared__ float sm[4], ssum[4];
  const int wv = tid >> 6, ln = tid & 63;
  if (ln == 0) { sm[wv] = m; ssum[wv] = s; }
  __syncthreads();
  if (tid == 0) {
    float M = sm[0], S = ssum[0];
    #pragma unroll
    for (int i = 1; i < 4; i++) {
      float nm = fmaxf(M, sm[i]);
      S = S * __expf(M - nm) + ssum[i] * __expf(sm[i] - nm);
      M = nm;
    }
    rowloss[row] = M + logf(S) - labellogit[row];
  }
}

// ---- kernel 4: mean over rows -> scalar ----
__global__ void k_mean(const float* __restrict__ rowloss, float* __restrict__ out) {
  const int tid = threadIdx.x;
  float v = rowloss[tid];
  #pragma unroll
  for (int msk = 1; msk < 64; msk <<= 1) v += __shfl_xor(v, msk);
  __shared__ float sred[8];
  if ((tid & 63) == 0) sred[tid >> 6] = v;
  __syncthreads();
  if (tid == 0) {
    float s = 0.f;
    #pragma unroll
    for (int i = 0; i < 8; i++) s += sred[i];
    out[0] = s / (float)BDIM;
  }
}

extern "C" void kernel_launch(void* const* d_in, const int* in_sizes, int n_in,
                              void* d_out, int out_size, void* d_ws, size_t ws_size,
                              hipStream_t stream) {
  const float* input = (const float*)d_in[0];
  const long long* label = (const long long*)d_in[1];
  const float* w = (const float*)d_in[2];
  float* out = (float*)d_out;

  char* ws = (char*)d_ws;
  // layout (bytes):
  //   a_bf16     @ 0         512 KB
  //   part       @ 524288    1563*512*8 = 6402048
  //   labellogit @ 6926336   2048
  //   rowloss    @ 6928384   2048
  //   invwn      @ 6930432   100032*4 = 400128
  //   w_t        @ 7330560   100032*512*2 = 102432768   (16B aligned)
  unsigned short* a_bf16 = (unsigned short*)(ws + 0);
  float2* part           = (float2*)(ws + 524288);
  float* labellogit      = (float*)(ws + 6926336);
  float* rowloss         = (float*)(ws + 6928384);
  float* invwn           = (float*)(ws + 6930432);
  unsigned short* w_t    = (unsigned short*)(ws + 7330560);

  k_rownorm<<<BDIM, 256, 0, stream>>>(input, a_bf16);
  k_wt<<<(CDIM + CTILE - 1) / CTILE, 512, 0, stream>>>(w, w_t, invwn);
  k_main<<<NCHUNK, 512, 0, stream>>>(a_bf16, w_t, invwn, label, part, labellogit);
  k_rowreduce<<<BDIM, 256, 0, stream>>>(part, labellogit, rowloss);
  k_mean<<<1, BDIM, 0, stream>>>(rowloss, out);
}